// Round 16
// baseline (422.073 us; speedup 1.0000x reference)
//
#include <hip/hip_runtime.h>

#define N_NODES 50000
#define N_EDGES 640000
#define EPS 1e-5f
#define NBLK_SCAN 196   // ceil(50000/256)
#define CGRID 3125      // xcvt blocks
#define NGRP 12500      // node groups (4 nodes each) for sliced gathers

typedef __attribute__((ext_vector_type(8))) short short8;
typedef __attribute__((ext_vector_type(4))) float f32x4;

__device__ inline unsigned short f2bf(float f) {
    unsigned u = __float_as_uint(f);
    u += 0x7fffu + ((u >> 16) & 1u);   // RNE
    return (unsigned short)(u >> 16);
}
__device__ inline float bf2f(unsigned short b) {
    return __uint_as_float(((unsigned)b) << 16);
}
__device__ inline void storev(short* p, float v) { *(unsigned short*)p = f2bf(v); }
__device__ inline void storev(float* p, float v) { *p = v; }

// ---------------- CSR build ----------------
__global__ void hist_kernel(const int* __restrict__ dst, int* __restrict__ counts,
                            int* __restrict__ erank) {
    int i = blockIdx.x * 256 + threadIdx.x;       // 8 edges per thread
    if (i >= N_EDGES / 8) return;
    int4 a = ((const int4*)dst)[2 * i];
    int4 b = ((const int4*)dst)[2 * i + 1];
    int4 ra, rb;
    ra.x = atomicAdd(&counts[a.x], 1);
    ra.y = atomicAdd(&counts[a.y], 1);
    ra.z = atomicAdd(&counts[a.z], 1);
    ra.w = atomicAdd(&counts[a.w], 1);
    rb.x = atomicAdd(&counts[b.x], 1);
    rb.y = atomicAdd(&counts[b.y], 1);
    rb.z = atomicAdd(&counts[b.z], 1);
    rb.w = atomicAdd(&counts[b.w], 1);
    ((int4*)erank)[2 * i]     = ra;
    ((int4*)erank)[2 * i + 1] = rb;
}

__global__ void scan1_kernel(const int* __restrict__ counts, int* __restrict__ incl,
                             int* __restrict__ bsums) {
    __shared__ int tmp[256];
    int t = threadIdx.x;
    int i = blockIdx.x * 256 + t;
    tmp[t] = (i < N_NODES) ? counts[i] : 0;
    __syncthreads();
    for (int off = 1; off < 256; off <<= 1) {
        int add = (t >= off) ? tmp[t - off] : 0;
        __syncthreads();
        tmp[t] += add;
        __syncthreads();
    }
    if (i < N_NODES) incl[i] = tmp[t];
    if (t == 255) bsums[blockIdx.x] = tmp[255];
}

__global__ void scan2_kernel(const int* __restrict__ bsums, int* __restrict__ boff) {
    __shared__ int tmp[256];
    int t = threadIdx.x;
    tmp[t] = (t < NBLK_SCAN) ? bsums[t] : 0;
    __syncthreads();
    for (int off = 1; off < 256; off <<= 1) {
        int add = (t >= off) ? tmp[t - off] : 0;
        __syncthreads();
        tmp[t] += add;
        __syncthreads();
    }
    if (t < NBLK_SCAN) boff[t] = (t == 0) ? 0 : tmp[t - 1];
}

__global__ void scan3_kernel(const int* __restrict__ counts, const int* __restrict__ incl,
                             const int* __restrict__ boff, int* __restrict__ rowptr,
                             float* __restrict__ rdeg) {
    int i = blockIdx.x * 256 + threadIdx.x;
    if (i >= N_NODES) return;
    int c = counts[i];
    int inc = incl[i] + boff[blockIdx.x];
    rowptr[i] = inc - c;
    rdeg[i] = 1.0f / fmaxf((float)c, 1.0f);
    if (i == N_NODES - 1) rowptr[N_NODES] = inc;
}

// atomic-free fill: slot = rowptr[dst] + rank
__global__ void fill_kernel(const int* __restrict__ src, const int* __restrict__ dst,
                            const int* __restrict__ erank, const int* __restrict__ rowptr,
                            int* __restrict__ esrc) {
    int i = blockIdx.x * 256 + threadIdx.x;       // 8 edges per thread
    if (i >= N_EDGES / 8) return;
    int4 da = ((const int4*)dst)[2 * i];
    int4 db = ((const int4*)dst)[2 * i + 1];
    int4 sa = ((const int4*)src)[2 * i];
    int4 sb = ((const int4*)src)[2 * i + 1];
    int4 ra = ((const int4*)erank)[2 * i];
    int4 rb = ((const int4*)erank)[2 * i + 1];
    esrc[rowptr[da.x] + ra.x] = sa.x;
    esrc[rowptr[da.y] + ra.y] = sa.y;
    esrc[rowptr[da.z] + ra.z] = sa.z;
    esrc[rowptr[da.w] + ra.w] = sa.w;
    esrc[rowptr[db.x] + rb.x] = sb.x;
    esrc[rowptr[db.y] + rb.y] = sb.y;
    esrc[rowptr[db.z] + rb.z] = sb.z;
    esrc[rowptr[db.w] + rb.w] = sb.w;
}

// ------- prep: x->bf16 SLICE-SPLIT [8][N][16] (+zero) AND pack weights -------
__global__ void prep_kernel(const float* __restrict__ in, short* __restrict__ outp,
                            int* __restrict__ counts, float* __restrict__ stats,
                            const float* __restrict__ W0, const float* __restrict__ W1,
                            const float* __restrict__ W2, const float* __restrict__ W3,
                            const float* __restrict__ W4, const float* __restrict__ W5,
                            short* __restrict__ P0, short* __restrict__ P1,
                            short* __restrict__ P2, short* __restrict__ P3,
                            short* __restrict__ P4, short* __restrict__ P5) {
    const size_t QS16 = (size_t)N_NODES * 16;
    int bi = blockIdx.x, t = threadIdx.x;
    if (bi < CGRID) {
        if (bi == 0 && t < 128) {
            float4 z = make_float4(0.f, 0.f, 0.f, 0.f);
            ((float4*)stats)[t] = z;              // 512 floats: sums0,sqs0,sums1,sqs1
        }
        if (bi >= 1 && bi <= NBLK_SCAN) {
            int idx = (bi - 1) * 256 + t;
            if (idx < N_NODES) counts[idx] = 0;
        }
        int i = bi * 256 + t;                     // 8-elem chunk
        if (i >= N_NODES * 16) return;
        const float4* p = (const float4*)in + 2 * (size_t)i;
        float4 a = p[0], b = p[1];
        short8 v;
        v[0] = (short)f2bf(a.x); v[1] = (short)f2bf(a.y);
        v[2] = (short)f2bf(a.z); v[3] = (short)f2bf(a.w);
        v[4] = (short)f2bf(b.x); v[5] = (short)f2bf(b.y);
        v[6] = (short)f2bf(b.z); v[7] = (short)f2bf(b.w);
        int row = i >> 4, c8 = i & 15;            // 8-col group: cols [8*c8, 8*c8+8)
        *(short8*)(outp + QS16 * (c8 >> 1) + (size_t)row * 16 + (c8 & 1) * 8) = v;
        return;
    }
    int b = bi - CGRID;
    const float* W; short* P; int NC; int base;
    if      (b < 8)  { W = W0; P = P0; NC = 128; base = 0;  }
    else if (b < 16) { W = W1; P = P1; NC = 128; base = 8;  }
    else if (b < 24) { W = W2; P = P2; NC = 128; base = 16; }
    else if (b < 32) { W = W3; P = P3; NC = 128; base = 24; }
    else if (b < 36) { W = W4; P = P4; NC = 64;  base = 32; }
    else             { W = W5; P = P5; NC = 64;  base = 36; }
    int idx = (b - base) * 256 + t;
    int total = 4 * (NC / 16) * 64;
    if (idx >= total) return;
    int lane = idx & 63;
    int cbks = idx >> 6;
    int cb = cbks % (NC / 16);
    int ks = cbks / (NC / 16);
    int col = cb * 16 + (lane & 15);
    int k0 = ks * 32 + ((lane >> 4) << 3);
    short8 v;
    #pragma unroll
    for (int j = 0; j < 8; ++j) v[j] = (short)f2bf(W[(size_t)(k0 + j) * NC + col]);
    *((short8*)P + idx) = v;
}

// ------- XCD-sliced gather: slice = blockIdx&7 (pins to one XCD's L2) --------
// activations in [8][N][16] slices (1.6MB each, L2-resident per XCD).
// wave = 1 node; lane = e*8+p: 8 edges/round, p = dword (2 cols) of slice row.
template<bool BN>
__global__ void gather_q(const short* __restrict__ h, const int* __restrict__ rowptr,
                         const int* __restrict__ esrc, const float* __restrict__ rdeg,
                         const float* __restrict__ sums, const float* __restrict__ sqs,
                         const float* __restrict__ g, const float* __restrict__ beta,
                         short* __restrict__ agg) {
    const size_t QS16 = (size_t)N_NODES * 16;
    int slice = blockIdx.x & 7;
    int node = (blockIdx.x >> 3) * 4 + (threadIdx.x >> 6);
    int lane = threadIdx.x & 63;
    if (node >= N_NODES) return;
    const int e = lane >> 3;          // edge slot 0..7
    const int p = lane & 7;           // dword (2 cols) within 16-col slice row
    const short* hq = h + QS16 * slice;

    float s0 = 0.f, s1 = 0.f, b0 = 0.f, b1 = 0.f;
    if (BN) {
        const float invN = 1.0f / N_NODES;
        int c = slice * 16 + p * 2;
        float2 sm = *(const float2*)(sums + c);
        float2 sq = *(const float2*)(sqs + c);
        float2 gg = *(const float2*)(g + c);
        float2 bb = *(const float2*)(beta + c);
        float m0 = sm.x * invN, m1 = sm.y * invN;
        float v0 = sq.x * invN - m0 * m0, v1 = sq.y * invN - m1 * m1;
        s0 = rsqrtf(v0 + EPS) * gg.x;
        s1 = rsqrtf(v1 + EPS) * gg.y;
        b0 = bb.x - m0 * s0;
        b1 = bb.y - m1 * s1;
    }

    int beg = rowptr[node], end = rowptr[node + 1];
    float a0 = 0.f, a1 = 0.f;
    while (beg < end) {
        int cnt = min(end - beg, 64);
        int mi = esrc[beg + min(lane, cnt - 1)];
        #pragma unroll 4
        for (int j = 0; j < cnt; j += 8) {
            int idx = j + e;
            int s = __shfl(mi, min(idx, cnt - 1));
            unsigned v = *(const unsigned*)(hq + (size_t)s * 16 + p * 2);
            if (idx < cnt) {
                float lo = __uint_as_float(v << 16);
                float hi = __uint_as_float(v & 0xffff0000u);
                if (BN) {
                    lo = fmaxf(fmaf(lo, s0, b0), 0.f);
                    hi = fmaxf(fmaf(hi, s1, b1), 0.f);
                }
                a0 += lo; a1 += hi;
            }
        }
        beg += cnt;
    }
    a0 += __shfl_xor(a0, 8); a0 += __shfl_xor(a0, 16); a0 += __shfl_xor(a0, 32);
    a1 += __shfl_xor(a1, 8); a1 += __shfl_xor(a1, 16); a1 += __shfl_xor(a1, 32);
    if (e == 0) {
        float r = rdeg[node];
        unsigned o = ((unsigned)f2bf(a1 * r) << 16) | (unsigned)f2bf(a0 * r);
        *(unsigned*)(agg + QS16 * slice + (size_t)node * 16 + p * 2) = o;
    }
}

// ---------------- MFMA SAGE linear (layers 0,1), slice-split I/O --------------
template<int NC, bool BNIN, bool STATS>
__global__ __launch_bounds__(512, 4)
void sage_mfma(const short* __restrict__ h, const short* __restrict__ agg,
               const short* __restrict__ Wpk,
               const float* __restrict__ bias,
               const float* __restrict__ sums_in, const float* __restrict__ sqs_in,
               const float* __restrict__ g_in, const float* __restrict__ beta_in,
               float* __restrict__ sums, float* __restrict__ sqs,
               short* __restrict__ out) {
    const size_t QS16 = (size_t)N_NODES * 16;
    constexpr int CBF = NC / 16;
    constexpr int WSH8 = CBF * 256;
    __shared__ short8 wlds[2 * WSH8];      // Ws then Wn  (64KB @ NC=128)
    __shared__ float ls[128], lq[128];
    const int t = threadIdx.x;
    const int lane = t & 63;
    const int w = t >> 6;
    const int wrow = blockIdx.x * 128 + w * 16;
    const int arow = wrow + (lane & 15);
    const int koff = (lane >> 4) << 3;

    {
        const short8* gw = (const short8*)Wpk;
        #pragma unroll
        for (int i = 0; i < (2 * WSH8) / 512; ++i)
            wlds[t + i * 512] = gw[t + i * 512];
    }
    if (BNIN) {
        if (t < 128) {
            const float invN = 1.0f / N_NODES;
            float m = sums_in[t] * invN;
            float v = sqs_in[t] * invN - m * m;
            float sc = rsqrtf(v + EPS) * g_in[t];
            ls[t] = sc;
            lq[t] = beta_in[t] - m * sc;
        }
    }
    __syncthreads();

    short8 zero8 = {0, 0, 0, 0, 0, 0, 0, 0};
    short8 A[8];
    if (arow < N_NODES) {
        #pragma unroll
        for (int ks = 0; ks < 4; ++ks) {
            int gc = ks * 32 + koff;       // global col of 8-elem group
            A[ks]     = *(const short8*)(h   + QS16 * (gc >> 4) + (size_t)arow * 16 + (gc & 15));
            A[4 + ks] = *(const short8*)(agg + QS16 * (gc >> 4) + (size_t)arow * 16 + (gc & 15));
        }
        if (BNIN) {
            #pragma unroll
            for (int ks = 0; ks < 4; ++ks) {
                int base = ks * 32 + koff;
                float4 sc0 = *(const float4*)&ls[base];
                float4 sc1 = *(const float4*)&ls[base + 4];
                float4 sh0 = *(const float4*)&lq[base];
                float4 sh1 = *(const float4*)&lq[base + 4];
                float scv[8] = {sc0.x, sc0.y, sc0.z, sc0.w, sc1.x, sc1.y, sc1.z, sc1.w};
                float shv[8] = {sh0.x, sh0.y, sh0.z, sh0.w, sh1.x, sh1.y, sh1.z, sh1.w};
                short8 v = A[ks];
                #pragma unroll
                for (int j = 0; j < 8; ++j) {
                    float f = bf2f((unsigned short)v[j]);
                    f = fmaxf(fmaf(f, scv[j], shv[j]), 0.f);
                    v[j] = (short)f2bf(f);
                }
                A[ks] = v;
            }
        }
    } else {
        #pragma unroll
        for (int s = 0; s < 8; ++s) A[s] = zero8;
    }

    if (STATS) {
        if (BNIN) __syncthreads();
        if (t < NC) { ls[t] = 0.f; lq[t] = 0.f; }
        __syncthreads();
    }

    f32x4 zacc = {0.f, 0.f, 0.f, 0.f};
    f32x4 acc[CBF];
    #pragma unroll
    for (int c = 0; c < CBF; ++c) acc[c] = zacc;

    #pragma unroll
    for (int s = 0; s < 8; ++s) {
        const int base = (s < 4) ? s * CBF * 64 : WSH8 + (s - 4) * CBF * 64;
        short8 af = A[s];
        #pragma unroll
        for (int c = 0; c < CBF; ++c) {
            short8 b = wlds[base + c * 64 + lane];
            acc[c] = __builtin_amdgcn_mfma_f32_16x16x32_bf16(af, b, acc[c], 0, 0, 0);
        }
    }

    const int col16 = lane & 15;
    const int rbase = wrow + ((lane >> 4) << 2);
    #pragma unroll
    for (int c = 0; c < CBF; ++c) {
        int gcol = c * 16 + col16;
        float bb = bias[gcol];
        float ps = 0.f, pq = 0.f;
        short* obase = out + QS16 * c;     // slice = c (cols [16c,16c+16))
        #pragma unroll
        for (int r = 0; r < 4; ++r) {
            int row = rbase + r;
            if (row < N_NODES) {
                float val = acc[c][r] + bb;
                storev(obase + (size_t)row * 16 + col16, val);
                if (STATS) { ps += val; pq += val * val; }
            }
        }
        if (STATS) {
            ps += __shfl_xor(ps, 16); ps += __shfl_xor(ps, 32);
            pq += __shfl_xor(pq, 16); pq += __shfl_xor(pq, 32);
            if (lane < 16) {
                atomicAdd(&ls[gcol], ps);
                atomicAdd(&lq[gcol], pq);
            }
        }
    }
    if (STATS) {
        __syncthreads();
        if (t < NC) {
            atomicAdd(&sums[t], ls[t]);
            atomicAdd(&sqs[t], lq[t]);
        }
    }
}

// -------- layer-2 dual GEMM: a2 = bn_relu(h2) [slice-split input];
//          y=a2@Ws2+b2 -> out (f32 [N][64]); z=a2@Wn2 -> z2 ([8][N][8] slices)
__global__ __launch_bounds__(512, 4)
void sage_mfma2(const short* __restrict__ h, const short* __restrict__ Wpk,
                const float* __restrict__ bias,
                const float* __restrict__ sums_in, const float* __restrict__ sqs_in,
                const float* __restrict__ g_in, const float* __restrict__ beta_in,
                float* __restrict__ out, short* __restrict__ z2) {
    const size_t QS16 = (size_t)N_NODES * 16;
    const size_t QS8 = (size_t)N_NODES * 8;
    constexpr int CBF = 4;                 // 64 cols
    constexpr int WSH8 = 1024;
    __shared__ short8 wlds[2 * WSH8];      // Ws2 then Wn2 (32KB)
    __shared__ float ls[128], lq[128];
    const int t = threadIdx.x;
    const int lane = t & 63;
    const int w = t >> 6;
    const int wrow = blockIdx.x * 128 + w * 16;
    const int arow = wrow + (lane & 15);
    const int koff = (lane >> 4) << 3;

    {
        const short8* gw = (const short8*)Wpk;
        #pragma unroll
        for (int i = 0; i < (2 * WSH8) / 512; ++i)
            wlds[t + i * 512] = gw[t + i * 512];
    }
    if (t < 128) {
        const float invN = 1.0f / N_NODES;
        float m = sums_in[t] * invN;
        float v = sqs_in[t] * invN - m * m;
        float sc = rsqrtf(v + EPS) * g_in[t];
        ls[t] = sc;
        lq[t] = beta_in[t] - m * sc;
    }
    __syncthreads();

    short8 zero8 = {0, 0, 0, 0, 0, 0, 0, 0};
    short8 A[4];
    if (arow < N_NODES) {
        #pragma unroll
        for (int ks = 0; ks < 4; ++ks) {
            int gc = ks * 32 + koff;
            int base = ks * 32 + koff;
            float4 sc0 = *(const float4*)&ls[base];
            float4 sc1 = *(const float4*)&ls[base + 4];
            float4 sh0 = *(const float4*)&lq[base];
            float4 sh1 = *(const float4*)&lq[base + 4];
            float scv[8] = {sc0.x, sc0.y, sc0.z, sc0.w, sc1.x, sc1.y, sc1.z, sc1.w};
            float shv[8] = {sh0.x, sh0.y, sh0.z, sh0.w, sh1.x, sh1.y, sh1.z, sh1.w};
            short8 v = *(const short8*)(h + QS16 * (gc >> 4) + (size_t)arow * 16 + (gc & 15));
            #pragma unroll
            for (int j = 0; j < 8; ++j) {
                float f = bf2f((unsigned short)v[j]);
                f = fmaxf(fmaf(f, scv[j], shv[j]), 0.f);
                v[j] = (short)f2bf(f);
            }
            A[ks] = v;
        }
    } else {
        #pragma unroll
        for (int s = 0; s < 4; ++s) A[s] = zero8;
    }

    f32x4 zacc = {0.f, 0.f, 0.f, 0.f};
    f32x4 accy[CBF], accz[CBF];
    #pragma unroll
    for (int c = 0; c < CBF; ++c) { accy[c] = zacc; accz[c] = zacc; }

    #pragma unroll
    for (int s = 0; s < 4; ++s) {
        short8 af = A[s];
        #pragma unroll
        for (int c = 0; c < CBF; ++c) {
            short8 by = wlds[s * 256 + c * 64 + lane];
            accy[c] = __builtin_amdgcn_mfma_f32_16x16x32_bf16(af, by, accy[c], 0, 0, 0);
        }
        #pragma unroll
        for (int c = 0; c < CBF; ++c) {
            short8 bz = wlds[WSH8 + s * 256 + c * 64 + lane];
            accz[c] = __builtin_amdgcn_mfma_f32_16x16x32_bf16(af, bz, accz[c], 0, 0, 0);
        }
    }

    const int col16 = lane & 15;
    const int rbase = wrow + ((lane >> 4) << 2);
    #pragma unroll
    for (int c = 0; c < CBF; ++c) {
        int gcol = c * 16 + col16;
        float bb = bias[gcol];
        short* zbase = z2 + QS8 * (gcol >> 3);
        int zoff = gcol & 7;
        #pragma unroll
        for (int r = 0; r < 4; ++r) {
            int row = rbase + r;
            if (row < N_NODES) {
                out[(size_t)row * 64 + gcol] = accy[c][r] + bb;
                storev(zbase + (size_t)row * 8 + zoff, accz[c][r]);
            }
        }
    }
}

// -------- XCD-sliced gather over [8][N][8] z2 slices, add mean into out ------
// slice = blockIdx&7 (0.8MB, L2-resident); lane = e*4+p: 16 edges/round.
__global__ void gather8_add(const short* __restrict__ z2, const int* __restrict__ rowptr,
                            const int* __restrict__ esrc, const float* __restrict__ rdeg,
                            float* __restrict__ out) {
    const size_t QS8 = (size_t)N_NODES * 8;
    int slice = blockIdx.x & 7;
    int node = (blockIdx.x >> 3) * 4 + (threadIdx.x >> 6);
    int lane = threadIdx.x & 63;
    if (node >= N_NODES) return;
    const int e = lane >> 2;          // edge slot 0..15
    const int p = lane & 3;           // dword (2 cols) within 8-col slice row
    const short* zq = z2 + QS8 * slice;

    int beg = rowptr[node], end = rowptr[node + 1];
    float a0 = 0.f, a1 = 0.f;
    while (beg < end) {
        int cnt = min(end - beg, 64);
        int mi = esrc[beg + min(lane, cnt - 1)];
        #pragma unroll 4
        for (int j = 0; j < cnt; j += 16) {
            int idx = j + e;
            int s = __shfl(mi, min(idx, cnt - 1));
            unsigned v = *(const unsigned*)(zq + (size_t)s * 8 + p * 2);
            if (idx < cnt) {
                a0 += __uint_as_float(v << 16);
                a1 += __uint_as_float(v & 0xffff0000u);
            }
        }
        beg += cnt;
    }
    a0 += __shfl_xor(a0, 4); a0 += __shfl_xor(a0, 8);
    a0 += __shfl_xor(a0, 16); a0 += __shfl_xor(a0, 32);
    a1 += __shfl_xor(a1, 4); a1 += __shfl_xor(a1, 8);
    a1 += __shfl_xor(a1, 16); a1 += __shfl_xor(a1, 32);
    if (e == 0) {
        float r = rdeg[node];
        float2* po = (float2*)(out + (size_t)node * 64 + slice * 8 + p * 2);
        float2 y = *po;
        y.x += a0 * r;
        y.y += a1 * r;
        *po = y;
    }
}

extern "C" void kernel_launch(void* const* d_in, const int* in_sizes, int n_in,
                              void* d_out, int out_size, void* d_ws, size_t ws_size,
                              hipStream_t stream) {
    const float* x   = (const float*)d_in[0];
    const int*   src = (const int*)d_in[1];
    const int*   dst = (const int*)d_in[2];
    const float* Ws0 = (const float*)d_in[3];
    const float* Wn0 = (const float*)d_in[4];
    const float* b0  = (const float*)d_in[5];
    const float* Ws1 = (const float*)d_in[6];
    const float* Wn1 = (const float*)d_in[7];
    const float* b1  = (const float*)d_in[8];
    const float* Ws2 = (const float*)d_in[9];
    const float* Wn2 = (const float*)d_in[10];
    const float* b2  = (const float*)d_in[11];
    const float* g0  = (const float*)d_in[12];
    const float* bt0 = (const float*)d_in[13];
    const float* g1  = (const float*)d_in[14];
    const float* bt1 = (const float*)d_in[15];

    char* ws = (char*)d_ws;
    const size_t HB2 = (size_t)N_NODES * 128 * 2;   // 12.8 MB (slice-split layout)
    size_t off = 0;
    short* xb     = (short*)(ws + off); off += HB2;
    short* aggb   = (short*)(ws + off); off += HB2;
    short* h1b    = (short*)(ws + off); off += HB2;
    short* h2b    = (short*)(ws + off); off += HB2;
    short* z2b    = (short*)(ws + off); off += (size_t)N_NODES * 64 * 2;  // 6.4MB
    int*   esrc   = (int*)(ws + off);   off += (size_t)N_EDGES * 4;
    int*   erank  = (int*)(ws + off);   off += (size_t)N_EDGES * 4;
    int*   counts = (int*)(ws + off);   off += 200192;
    int*   incl   = (int*)(ws + off);   off += 200192;
    int*   rowptr = (int*)(ws + off);   off += 200704;
    float* rdeg   = (float*)(ws + off); off += 200192;
    int*   bsums  = (int*)(ws + off);   off += 1024;
    int*   boff   = (int*)(ws + off);   off += 1024;
    float* stats  = (float*)(ws + off); off += 2048;   // sums0,sqs0,sums1,sqs1
    float* sums0  = stats;
    float* sqs0   = stats + 128;
    float* sums1  = stats + 256;
    float* sqs1   = stats + 384;
    short* pW0    = (short*)(ws + off); off += 65536;
    short* pW1    = (short*)(ws + off); off += 65536;
    short* pW2    = (short*)(ws + off); off += 32768;

    float* out = (float*)d_out;

    const int e8grid = (N_EDGES / 8 + 255) / 256;   // 313
    const int mgrid  = (N_NODES + 127) / 128;       // 391
    const int sggrid = NGRP * 8;                    // 100000 sliced-gather blocks

    // ---- prep: x->bf16 (slice-split) + zero + weight packing, then CSR ----
    prep_kernel<<<CGRID + 40, 256, 0, stream>>>(
        x, xb, counts, stats, Ws0, Wn0, Ws1, Wn1, Ws2, Wn2,
        pW0, pW0 + 16384, pW1, pW1 + 16384, pW2, pW2 + 8192);
    hist_kernel<<<e8grid, 256, 0, stream>>>(dst, counts, erank);
    scan1_kernel<<<NBLK_SCAN, 256, 0, stream>>>(counts, incl, bsums);
    scan2_kernel<<<1, 256, 0, stream>>>(bsums, boff);
    scan3_kernel<<<NBLK_SCAN, 256, 0, stream>>>(counts, incl, boff, rowptr, rdeg);
    fill_kernel<<<e8grid, 256, 0, stream>>>(src, dst, erank, rowptr, esrc);

    // ---- layer 0 ----
    gather_q<false><<<sggrid, 256, 0, stream>>>(xb, rowptr, esrc, rdeg,
                                                nullptr, nullptr, nullptr, nullptr, aggb);
    sage_mfma<128, false, true><<<mgrid, 512, 0, stream>>>(
        xb, aggb, pW0, b0, nullptr, nullptr, nullptr, nullptr, sums0, sqs0, h1b);

    // ---- layer 1 ----
    gather_q<true><<<sggrid, 256, 0, stream>>>(h1b, rowptr, esrc, rdeg,
                                               sums0, sqs0, g0, bt0, aggb);
    sage_mfma<128, true, true><<<mgrid, 512, 0, stream>>>(
        h1b, aggb, pW1, b1, sums0, sqs0, g0, bt0, sums1, sqs1, h2b);

    // ---- layer 2 (agg commuted past Wn2; XCD-sliced gather on z2) ----
    sage_mfma2<<<mgrid, 512, 0, stream>>>(
        h2b, pW2, b2, sums1, sqs1, g1, bt1, out, z2b);
    gather8_add<<<sggrid, 256, 0, stream>>>(z2b, rowptr, esrc, rdeg, out);
}

// Round 17
// 193.361 us; speedup vs baseline: 2.1828x; 2.1828x over previous
//
#include <hip/hip_runtime.h>

#define N_NODES 50000
#define N_EDGES 640000
#define EPS 1e-5f
#define NBLK_SCAN 196   // ceil(50000/256)
#define CGRID 3125      // xcvt blocks

typedef __attribute__((ext_vector_type(8))) short short8;
typedef __attribute__((ext_vector_type(4))) float f32x4;

__device__ inline unsigned short f2bf(float f) {
    unsigned u = __float_as_uint(f);
    u += 0x7fffu + ((u >> 16) & 1u);   // RNE
    return (unsigned short)(u >> 16);
}
__device__ inline float bf2f(unsigned short b) {
    return __uint_as_float(((unsigned)b) << 16);
}
__device__ inline void storev(short* p, float v) { *(unsigned short*)p = f2bf(v); }
__device__ inline void storev(float* p, float v) { *p = v; }

// ---------------- CSR build ----------------
__global__ void hist_kernel(const int* __restrict__ dst, int* __restrict__ counts,
                            int* __restrict__ erank) {
    int i = blockIdx.x * 256 + threadIdx.x;       // 8 edges per thread
    if (i >= N_EDGES / 8) return;
    int4 a = ((const int4*)dst)[2 * i];
    int4 b = ((const int4*)dst)[2 * i + 1];
    int4 ra, rb;
    ra.x = atomicAdd(&counts[a.x], 1);
    ra.y = atomicAdd(&counts[a.y], 1);
    ra.z = atomicAdd(&counts[a.z], 1);
    ra.w = atomicAdd(&counts[a.w], 1);
    rb.x = atomicAdd(&counts[b.x], 1);
    rb.y = atomicAdd(&counts[b.y], 1);
    rb.z = atomicAdd(&counts[b.z], 1);
    rb.w = atomicAdd(&counts[b.w], 1);
    ((int4*)erank)[2 * i]     = ra;
    ((int4*)erank)[2 * i + 1] = rb;
}

__global__ void scan1_kernel(const int* __restrict__ counts, int* __restrict__ incl,
                             int* __restrict__ bsums) {
    __shared__ int tmp[256];
    int t = threadIdx.x;
    int i = blockIdx.x * 256 + t;
    tmp[t] = (i < N_NODES) ? counts[i] : 0;
    __syncthreads();
    for (int off = 1; off < 256; off <<= 1) {
        int add = (t >= off) ? tmp[t - off] : 0;
        __syncthreads();
        tmp[t] += add;
        __syncthreads();
    }
    if (i < N_NODES) incl[i] = tmp[t];
    if (t == 255) bsums[blockIdx.x] = tmp[255];
}

__global__ void scan2_kernel(const int* __restrict__ bsums, int* __restrict__ boff) {
    __shared__ int tmp[256];
    int t = threadIdx.x;
    tmp[t] = (t < NBLK_SCAN) ? bsums[t] : 0;
    __syncthreads();
    for (int off = 1; off < 256; off <<= 1) {
        int add = (t >= off) ? tmp[t - off] : 0;
        __syncthreads();
        tmp[t] += add;
        __syncthreads();
    }
    if (t < NBLK_SCAN) boff[t] = (t == 0) ? 0 : tmp[t - 1];
}

__global__ void scan3_kernel(const int* __restrict__ counts, const int* __restrict__ incl,
                             const int* __restrict__ boff, int* __restrict__ rowptr,
                             float* __restrict__ rdeg) {
    int i = blockIdx.x * 256 + threadIdx.x;
    if (i >= N_NODES) return;
    int c = counts[i];
    int inc = incl[i] + boff[blockIdx.x];
    rowptr[i] = inc - c;
    rdeg[i] = 1.0f / fmaxf((float)c, 1.0f);
    if (i == N_NODES - 1) rowptr[N_NODES] = inc;
}

// atomic-free fill: slot = rowptr[dst] + rank
__global__ void fill_kernel(const int* __restrict__ src, const int* __restrict__ dst,
                            const int* __restrict__ erank, const int* __restrict__ rowptr,
                            int* __restrict__ esrc) {
    int i = blockIdx.x * 256 + threadIdx.x;       // 8 edges per thread
    if (i >= N_EDGES / 8) return;
    int4 da = ((const int4*)dst)[2 * i];
    int4 db = ((const int4*)dst)[2 * i + 1];
    int4 sa = ((const int4*)src)[2 * i];
    int4 sb = ((const int4*)src)[2 * i + 1];
    int4 ra = ((const int4*)erank)[2 * i];
    int4 rb = ((const int4*)erank)[2 * i + 1];
    esrc[rowptr[da.x] + ra.x] = sa.x;
    esrc[rowptr[da.y] + ra.y] = sa.y;
    esrc[rowptr[da.z] + ra.z] = sa.z;
    esrc[rowptr[da.w] + ra.w] = sa.w;
    esrc[rowptr[db.x] + rb.x] = sb.x;
    esrc[rowptr[db.y] + rb.y] = sb.y;
    esrc[rowptr[db.z] + rb.z] = sb.z;
    esrc[rowptr[db.w] + rb.w] = sb.w;
}

// ------- prep: x->bf16 (+zero counts/stats) AND pack all 6 weight mats -------
// blocks [0,CGRID): xcvt; blocks [CGRID, CGRID+40): weight packing.
__global__ void prep_kernel(const float* __restrict__ in, short* __restrict__ outp,
                            int* __restrict__ counts, float* __restrict__ stats,
                            const float* __restrict__ W0, const float* __restrict__ W1,
                            const float* __restrict__ W2, const float* __restrict__ W3,
                            const float* __restrict__ W4, const float* __restrict__ W5,
                            short* __restrict__ P0, short* __restrict__ P1,
                            short* __restrict__ P2, short* __restrict__ P3,
                            short* __restrict__ P4, short* __restrict__ P5) {
    int bi = blockIdx.x, t = threadIdx.x;
    if (bi < CGRID) {
        if (bi == 0 && t < 128) {
            float4 z = make_float4(0.f, 0.f, 0.f, 0.f);
            ((float4*)stats)[t] = z;              // 512 floats: sums0,sqs0,sums1,sqs1
        }
        if (bi >= 1 && bi <= NBLK_SCAN) {
            int idx = (bi - 1) * 256 + t;
            if (idx < N_NODES) counts[idx] = 0;
        }
        int i = bi * 256 + t;                     // 8-elem chunk
        if (i >= N_NODES * 16) return;
        const float4* p = (const float4*)in + 2 * (size_t)i;
        float4 a = p[0], b = p[1];
        short8 v;
        v[0] = (short)f2bf(a.x); v[1] = (short)f2bf(a.y);
        v[2] = (short)f2bf(a.z); v[3] = (short)f2bf(a.w);
        v[4] = (short)f2bf(b.x); v[5] = (short)f2bf(b.y);
        v[6] = (short)f2bf(b.z); v[7] = (short)f2bf(b.w);
        *((short8*)outp + i) = v;
        return;
    }
    int b = bi - CGRID;
    const float* W; short* P; int NC; int base;
    if      (b < 8)  { W = W0; P = P0; NC = 128; base = 0;  }
    else if (b < 16) { W = W1; P = P1; NC = 128; base = 8;  }
    else if (b < 24) { W = W2; P = P2; NC = 128; base = 16; }
    else if (b < 32) { W = W3; P = P3; NC = 128; base = 24; }
    else if (b < 36) { W = W4; P = P4; NC = 64;  base = 32; }
    else             { W = W5; P = P5; NC = 64;  base = 36; }
    int idx = (b - base) * 256 + t;
    int total = 4 * (NC / 16) * 64;
    if (idx >= total) return;
    int lane = idx & 63;
    int cbks = idx >> 6;
    int cb = cbks % (NC / 16);
    int ks = cbks / (NC / 16);
    int col = cb * 16 + (lane & 15);
    int k0 = ks * 32 + ((lane >> 4) << 3);
    short8 v;
    #pragma unroll
    for (int j = 0; j < 8; ++j) v[j] = (short)f2bf(W[(size_t)(k0 + j) * NC + col]);
    *((short8*)P + idx) = v;
}

// ---------------- gather mean (128-feat rows), fused BN(from stats)+ReLU ------
template<bool BN>
__global__ void gather_k(const short* __restrict__ h, const int* __restrict__ rowptr,
                         const int* __restrict__ esrc, const float* __restrict__ rdeg,
                         const float* __restrict__ sums, const float* __restrict__ sqs,
                         const float* __restrict__ g, const float* __restrict__ beta,
                         short* __restrict__ agg) {
    int node = blockIdx.x * 4 + (threadIdx.x >> 6);
    int lane = threadIdx.x & 63;
    if (node >= N_NODES) return;
    int beg = rowptr[node], end = rowptr[node + 1];
    float s0 = 0.f, s1 = 0.f, b0 = 0.f, b1 = 0.f;
    if (BN) {
        const float invN = 1.0f / N_NODES;
        float2 sm = *(const float2*)(sums + lane * 2);
        float2 sq = *(const float2*)(sqs + lane * 2);
        float2 gg = *(const float2*)(g + lane * 2);
        float2 bb = *(const float2*)(beta + lane * 2);
        float m0 = sm.x * invN, m1 = sm.y * invN;
        float v0 = sq.x * invN - m0 * m0, v1 = sq.y * invN - m1 * m1;
        s0 = rsqrtf(v0 + EPS) * gg.x;
        s1 = rsqrtf(v1 + EPS) * gg.y;
        b0 = bb.x - m0 * s0;
        b1 = bb.y - m1 * s1;
    }
    float ax = 0.f, ay = 0.f;
    while (beg < end) {
        int cnt = min(end - beg, 64);
        int mi = esrc[beg + min(lane, cnt - 1)];
        for (int j = 0; j < cnt; j += 16) {
            int lim = cnt - j; if (lim > 16) lim = 16;
            unsigned v[16];
            #pragma unroll
            for (int u = 0; u < 16; ++u) {
                int s = __shfl(mi, j + (u < lim ? u : lim - 1));
                v[u] = *(const unsigned*)(h + (size_t)s * 128 + lane * 2);
            }
            #pragma unroll
            for (int u = 0; u < 16; ++u) {
                if (u < lim) {
                    float lo = __uint_as_float(v[u] << 16);
                    float hi = __uint_as_float(v[u] & 0xffff0000u);
                    if (BN) {
                        lo = fmaxf(fmaf(lo, s0, b0), 0.f);
                        hi = fmaxf(fmaf(hi, s1, b1), 0.f);
                    }
                    ax += lo; ay += hi;
                }
            }
        }
        beg += cnt;
    }
    float r = rdeg[node];
    unsigned o = ((unsigned)f2bf(ay * r) << 16) | (unsigned)f2bf(ax * r);
    *(unsigned*)(agg + (size_t)node * 128 + lane * 2) = o;
}

// ---------------- MFMA SAGE linear (layers 0,1): out = BN?(h)@Ws + agg@Wn + b -
template<int NC, bool BNIN, bool STATS, typename OUT>
__global__ __launch_bounds__(512, 4)
void sage_mfma(const short* __restrict__ h, const short* __restrict__ agg,
               const short* __restrict__ Wpk,
               const float* __restrict__ bias,
               const float* __restrict__ sums_in, const float* __restrict__ sqs_in,
               const float* __restrict__ g_in, const float* __restrict__ beta_in,
               float* __restrict__ sums, float* __restrict__ sqs,
               OUT* __restrict__ out) {
    constexpr int CBF = NC / 16;
    constexpr int WSH8 = CBF * 256;
    __shared__ short8 wlds[2 * WSH8];      // Ws then Wn  (64KB @ NC=128)
    __shared__ float ls[128], lq[128];
    const int t = threadIdx.x;
    const int lane = t & 63;
    const int w = t >> 6;
    const int wrow = blockIdx.x * 128 + w * 16;
    const int arow = wrow + (lane & 15);
    const int koff = (lane >> 4) << 3;

    {
        const short8* gw = (const short8*)Wpk;
        #pragma unroll
        for (int i = 0; i < (2 * WSH8) / 512; ++i)
            wlds[t + i * 512] = gw[t + i * 512];
    }
    if (BNIN) {
        if (t < 128) {
            const float invN = 1.0f / N_NODES;
            float m = sums_in[t] * invN;
            float v = sqs_in[t] * invN - m * m;
            float sc = rsqrtf(v + EPS) * g_in[t];
            ls[t] = sc;
            lq[t] = beta_in[t] - m * sc;
        }
    }
    __syncthreads();

    short8 zero8 = {0, 0, 0, 0, 0, 0, 0, 0};
    short8 A[8];
    if (arow < N_NODES) {
        const short8* hb = (const short8*)(h + (size_t)arow * 128 + koff);
        const short8* ab = (const short8*)(agg + (size_t)arow * 128 + koff);
        #pragma unroll
        for (int ks = 0; ks < 4; ++ks) {
            A[ks] = hb[ks * 4];
            A[4 + ks] = ab[ks * 4];
        }
        if (BNIN) {
            #pragma unroll
            for (int ks = 0; ks < 4; ++ks) {
                int base = ks * 32 + koff;
                float4 sc0 = *(const float4*)&ls[base];
                float4 sc1 = *(const float4*)&ls[base + 4];
                float4 sh0 = *(const float4*)&lq[base];
                float4 sh1 = *(const float4*)&lq[base + 4];
                float scv[8] = {sc0.x, sc0.y, sc0.z, sc0.w, sc1.x, sc1.y, sc1.z, sc1.w};
                float shv[8] = {sh0.x, sh0.y, sh0.z, sh0.w, sh1.x, sh1.y, sh1.z, sh1.w};
                short8 v = A[ks];
                #pragma unroll
                for (int j = 0; j < 8; ++j) {
                    float f = bf2f((unsigned short)v[j]);
                    f = fmaxf(fmaf(f, scv[j], shv[j]), 0.f);
                    v[j] = (short)f2bf(f);
                }
                A[ks] = v;
            }
        }
    } else {
        #pragma unroll
        for (int s = 0; s < 8; ++s) A[s] = zero8;
    }

    if (STATS) {
        if (BNIN) __syncthreads();
        if (t < NC) { ls[t] = 0.f; lq[t] = 0.f; }
        __syncthreads();
    }

    f32x4 zacc = {0.f, 0.f, 0.f, 0.f};
    f32x4 acc[CBF];
    #pragma unroll
    for (int c = 0; c < CBF; ++c) acc[c] = zacc;

    #pragma unroll
    for (int s = 0; s < 8; ++s) {
        const int base = (s < 4) ? s * CBF * 64 : WSH8 + (s - 4) * CBF * 64;
        short8 af = A[s];
        #pragma unroll
        for (int c = 0; c < CBF; ++c) {
            short8 b = wlds[base + c * 64 + lane];
            acc[c] = __builtin_amdgcn_mfma_f32_16x16x32_bf16(af, b, acc[c], 0, 0, 0);
        }
    }

    const int col16 = lane & 15;
    const int rbase = wrow + ((lane >> 4) << 2);
    #pragma unroll
    for (int c = 0; c < CBF; ++c) {
        int gcol = c * 16 + col16;
        float bb = bias[gcol];
        float ps = 0.f, pq = 0.f;
        #pragma unroll
        for (int r = 0; r < 4; ++r) {
            int row = rbase + r;
            if (row < N_NODES) {
                float val = acc[c][r] + bb;
                storev(out + (size_t)row * NC + gcol, val);
                if (STATS) { ps += val; pq += val * val; }
            }
        }
        if (STATS) {
            ps += __shfl_xor(ps, 16); ps += __shfl_xor(ps, 32);
            pq += __shfl_xor(pq, 16); pq += __shfl_xor(pq, 32);
            if (lane < 16) {
                atomicAdd(&ls[gcol], ps);
                atomicAdd(&lq[gcol], pq);
            }
        }
    }
    if (STATS) {
        __syncthreads();
        if (t < NC) {
            atomicAdd(&sums[t], ls[t]);
            atomicAdd(&sqs[t], lq[t]);
        }
    }
}

// -------- layer-2 dual GEMM: a2 = bn_relu(h2); y=a2@Ws2+b2 -> out (f32);
//          z=a2@Wn2 -> z2 (bf16). agg commutes with Wn2 (linear), so the
//          gather afterwards runs on 64-col z2 rows (2 cache lines/edge). -----
__global__ __launch_bounds__(512, 4)
void sage_mfma2(const short* __restrict__ h, const short* __restrict__ Wpk,
                const float* __restrict__ bias,
                const float* __restrict__ sums_in, const float* __restrict__ sqs_in,
                const float* __restrict__ g_in, const float* __restrict__ beta_in,
                float* __restrict__ out, short* __restrict__ z2) {
    constexpr int CBF = 4;                 // 64 cols
    constexpr int WSH8 = 1024;             // short8 per packed matrix
    __shared__ short8 wlds[2 * WSH8];      // Ws2 then Wn2 (32KB)
    __shared__ float ls[128], lq[128];
    const int t = threadIdx.x;
    const int lane = t & 63;
    const int w = t >> 6;
    const int wrow = blockIdx.x * 128 + w * 16;
    const int arow = wrow + (lane & 15);
    const int koff = (lane >> 4) << 3;

    {
        const short8* gw = (const short8*)Wpk;
        #pragma unroll
        for (int i = 0; i < (2 * WSH8) / 512; ++i)
            wlds[t + i * 512] = gw[t + i * 512];
    }
    if (t < 128) {
        const float invN = 1.0f / N_NODES;
        float m = sums_in[t] * invN;
        float v = sqs_in[t] * invN - m * m;
        float sc = rsqrtf(v + EPS) * g_in[t];
        ls[t] = sc;
        lq[t] = beta_in[t] - m * sc;
    }
    __syncthreads();

    short8 zero8 = {0, 0, 0, 0, 0, 0, 0, 0};
    short8 A[4];                           // a2 = bn_relu(h2) K-slices
    if (arow < N_NODES) {
        const short8* hb = (const short8*)(h + (size_t)arow * 128 + koff);
        #pragma unroll
        for (int ks = 0; ks < 4; ++ks) {
            int base = ks * 32 + koff;
            float4 sc0 = *(const float4*)&ls[base];
            float4 sc1 = *(const float4*)&ls[base + 4];
            float4 sh0 = *(const float4*)&lq[base];
            float4 sh1 = *(const float4*)&lq[base + 4];
            float scv[8] = {sc0.x, sc0.y, sc0.z, sc0.w, sc1.x, sc1.y, sc1.z, sc1.w};
            float shv[8] = {sh0.x, sh0.y, sh0.z, sh0.w, sh1.x, sh1.y, sh1.z, sh1.w};
            short8 v = hb[ks * 4];
            #pragma unroll
            for (int j = 0; j < 8; ++j) {
                float f = bf2f((unsigned short)v[j]);
                f = fmaxf(fmaf(f, scv[j], shv[j]), 0.f);
                v[j] = (short)f2bf(f);
            }
            A[ks] = v;
        }
    } else {
        #pragma unroll
        for (int s = 0; s < 4; ++s) A[s] = zero8;
    }

    f32x4 zacc = {0.f, 0.f, 0.f, 0.f};
    f32x4 accy[CBF], accz[CBF];
    #pragma unroll
    for (int c = 0; c < CBF; ++c) { accy[c] = zacc; accz[c] = zacc; }

    #pragma unroll
    for (int s = 0; s < 4; ++s) {
        short8 af = A[s];
        #pragma unroll
        for (int c = 0; c < CBF; ++c) {
            short8 by = wlds[s * 256 + c * 64 + lane];
            accy[c] = __builtin_amdgcn_mfma_f32_16x16x32_bf16(af, by, accy[c], 0, 0, 0);
        }
        #pragma unroll
        for (int c = 0; c < CBF; ++c) {
            short8 bz = wlds[WSH8 + s * 256 + c * 64 + lane];
            accz[c] = __builtin_amdgcn_mfma_f32_16x16x32_bf16(af, bz, accz[c], 0, 0, 0);
        }
    }

    const int col16 = lane & 15;
    const int rbase = wrow + ((lane >> 4) << 2);
    #pragma unroll
    for (int c = 0; c < CBF; ++c) {
        int gcol = c * 16 + col16;
        float bb = bias[gcol];
        #pragma unroll
        for (int r = 0; r < 4; ++r) {
            int row = rbase + r;
            if (row < N_NODES) {
                out[(size_t)row * 64 + gcol] = accy[c][r] + bb;
                storev(z2 + (size_t)row * 64 + gcol, accz[c][r]);
            }
        }
    }
}

// -------- gather over 64-col z2 rows (2 edges/wave/instr), add mean to out ----
__global__ void gather64_add(const short* __restrict__ z2, const int* __restrict__ rowptr,
                             const int* __restrict__ esrc, const float* __restrict__ rdeg,
                             float* __restrict__ out) {
    int node = blockIdx.x * 4 + (threadIdx.x >> 6);
    int lane = threadIdx.x & 63;
    if (node >= N_NODES) return;
    const int e = lane >> 5;          // edge slot 0/1
    const int p = lane & 31;          // dword (2 feats) within row
    int beg = rowptr[node], end = rowptr[node + 1];
    float a0 = 0.f, a1 = 0.f;
    while (beg < end) {
        int cnt = min(end - beg, 64);
        int mi = esrc[beg + min(lane, cnt - 1)];
        for (int j = 0; j < cnt; j += 16) {
            unsigned v[8];
            #pragma unroll
            for (int u = 0; u < 8; ++u) {
                int idx = j + 2 * u + e;
                int s = __shfl(mi, min(idx, cnt - 1));
                v[u] = *(const unsigned*)(z2 + (size_t)s * 64 + p * 2);
            }
            #pragma unroll
            for (int u = 0; u < 8; ++u) {
                int idx = j + 2 * u + e;
                if (idx < cnt) {
                    a0 += __uint_as_float(v[u] << 16);
                    a1 += __uint_as_float(v[u] & 0xffff0000u);
                }
            }
        }
        beg += cnt;
    }
    a0 += __shfl_xor(a0, 32);
    a1 += __shfl_xor(a1, 32);
    if (e == 0) {
        float r = rdeg[node];
        float2* po = (float2*)(out + (size_t)node * 64 + p * 2);
        float2 y = *po;
        y.x += a0 * r;
        y.y += a1 * r;
        *po = y;
    }
}

extern "C" void kernel_launch(void* const* d_in, const int* in_sizes, int n_in,
                              void* d_out, int out_size, void* d_ws, size_t ws_size,
                              hipStream_t stream) {
    const float* x   = (const float*)d_in[0];
    const int*   src = (const int*)d_in[1];
    const int*   dst = (const int*)d_in[2];
    const float* Ws0 = (const float*)d_in[3];
    const float* Wn0 = (const float*)d_in[4];
    const float* b0  = (const float*)d_in[5];
    const float* Ws1 = (const float*)d_in[6];
    const float* Wn1 = (const float*)d_in[7];
    const float* b1  = (const float*)d_in[8];
    const float* Ws2 = (const float*)d_in[9];
    const float* Wn2 = (const float*)d_in[10];
    const float* b2  = (const float*)d_in[11];
    const float* g0  = (const float*)d_in[12];
    const float* bt0 = (const float*)d_in[13];
    const float* g1  = (const float*)d_in[14];
    const float* bt1 = (const float*)d_in[15];

    char* ws = (char*)d_ws;
    const size_t HB2 = (size_t)N_NODES * 128 * 2;   // bf16 tensor: 12.8 MB
    size_t off = 0;
    short* xb     = (short*)(ws + off); off += HB2;
    short* aggb   = (short*)(ws + off); off += HB2;
    short* h1b    = (short*)(ws + off); off += HB2;
    short* h2b    = (short*)(ws + off); off += HB2;
    short* z2b    = (short*)(ws + off); off += (size_t)N_NODES * 64 * 2;  // 6.4MB
    int*   esrc   = (int*)(ws + off);   off += (size_t)N_EDGES * 4;
    int*   erank  = (int*)(ws + off);   off += (size_t)N_EDGES * 4;
    int*   counts = (int*)(ws + off);   off += 200192;
    int*   incl   = (int*)(ws + off);   off += 200192;
    int*   rowptr = (int*)(ws + off);   off += 200704;
    float* rdeg   = (float*)(ws + off); off += 200192;
    int*   bsums  = (int*)(ws + off);   off += 1024;
    int*   boff   = (int*)(ws + off);   off += 1024;
    float* stats  = (float*)(ws + off); off += 2048;   // sums0,sqs0,sums1,sqs1
    float* sums0  = stats;
    float* sqs0   = stats + 128;
    float* sums1  = stats + 256;
    float* sqs1   = stats + 384;
    short* pW0    = (short*)(ws + off); off += 65536;
    short* pW1    = (short*)(ws + off); off += 65536;
    short* pW2    = (short*)(ws + off); off += 32768;

    float* out = (float*)d_out;

    const int e8grid = (N_EDGES / 8 + 255) / 256;   // 313
    const int ggrid  = (N_NODES + 3) / 4;           // 12500
    const int mgrid  = (N_NODES + 127) / 128;       // 391

    // ---- prep: x->bf16 + zero + weight packing (one kernel), then CSR ----
    prep_kernel<<<CGRID + 40, 256, 0, stream>>>(
        x, xb, counts, stats, Ws0, Wn0, Ws1, Wn1, Ws2, Wn2,
        pW0, pW0 + 16384, pW1, pW1 + 16384, pW2, pW2 + 8192);
    hist_kernel<<<e8grid, 256, 0, stream>>>(dst, counts, erank);
    scan1_kernel<<<NBLK_SCAN, 256, 0, stream>>>(counts, incl, bsums);
    scan2_kernel<<<1, 256, 0, stream>>>(bsums, boff);
    scan3_kernel<<<NBLK_SCAN, 256, 0, stream>>>(counts, incl, boff, rowptr, rdeg);
    fill_kernel<<<e8grid, 256, 0, stream>>>(src, dst, erank, rowptr, esrc);

    // ---- layer 0 ----
    gather_k<false><<<ggrid, 256, 0, stream>>>(xb, rowptr, esrc, rdeg,
                                               nullptr, nullptr, nullptr, nullptr, aggb);
    sage_mfma<128, false, true, short><<<mgrid, 512, 0, stream>>>(
        xb, aggb, pW0, b0, nullptr, nullptr, nullptr, nullptr, sums0, sqs0, h1b);

    // ---- layer 1 ----
    gather_k<true><<<ggrid, 256, 0, stream>>>(h1b, rowptr, esrc, rdeg,
                                              sums0, sqs0, g0, bt0, aggb);
    sage_mfma<128, true, true, short><<<mgrid, 512, 0, stream>>>(
        h1b, aggb, pW1, b1, sums0, sqs0, g0, bt0, sums1, sqs1, h2b);

    // ---- layer 2 (agg commuted past Wn2) ----
    sage_mfma2<<<mgrid, 512, 0, stream>>>(
        h2b, pW2, b2, sums1, sqs1, g1, bt1, out, z2b);
    gather64_add<<<ggrid, 256, 0, stream>>>(z2b, rowptr, esrc, rdeg, out);
}